// Round 1
// baseline (385.923 us; speedup 1.0000x reference)
//
#include <hip/hip_runtime.h>
#include <hip/hip_bf16.h>

typedef __attribute__((ext_vector_type(4))) float fx4;
typedef __attribute__((ext_vector_type(8))) short bx8;

#define GLD16(dst, src)                                                        \
  __builtin_amdgcn_global_load_lds(                                            \
      (__attribute__((address_space(1))) void*)(src),                          \
      (__attribute__((address_space(3))) void*)(dst), 16, 0, 0)

// ---------------------------------------------------------------- cast x->bf16
__global__ __launch_bounds__(256) void k_cast(const float* __restrict__ in,
                                              __hip_bfloat16* __restrict__ out,
                                              int n4) {
  int i = blockIdx.x * 256 + threadIdx.x;
  if (i >= n4) return;
  float4 v = reinterpret_cast<const float4*>(in)[i];
  __hip_bfloat16 t[4] = {__float2bfloat16(v.x), __float2bfloat16(v.y),
                         __float2bfloat16(v.z), __float2bfloat16(v.w)};
  reinterpret_cast<ushort4*>(out)[i] = *reinterpret_cast<ushort4*>(t);
}

// ------------------------------------------- transpose-cast fp32 RxC -> bf16 CxR
__global__ void k_tcast(const float* __restrict__ in,
                        __hip_bfloat16* __restrict__ out, int R, int C) {
  __shared__ float tile[32][33];
  int c0 = blockIdx.x * 32, r0 = blockIdx.y * 32;
  int tx = threadIdx.x, ty = threadIdx.y;
#pragma unroll
  for (int j = 0; j < 4; ++j)
    tile[ty + j * 8][tx] = in[(size_t)(r0 + ty + j * 8) * C + c0 + tx];
  __syncthreads();
#pragma unroll
  for (int j = 0; j < 4; ++j)
    out[(size_t)(c0 + ty + j * 8) * R + r0 + tx] =
        __float2bfloat16(tile[tx][ty + j * 8]);
}

// ----------------------------------------------------------- rope cos/sin table
__global__ __launch_bounds__(256) void k_ropetab(float* __restrict__ cosT,
                                                 float* __restrict__ sinT) {
  int idx = blockIdx.x * 256 + threadIdx.x;  // 2048*64
  int t = idx >> 6, i = idx & 63;
  float inv = expf(-logf(10000.0f) * (float)i * (1.0f / 64.0f));
  float fr = (float)t * inv;
  cosT[idx] = cosf(fr);
  sinT[idx] = sinf(fr);
}

// ------------------------------------------------- apply rope to q,k (in place)
__global__ __launch_bounds__(256) void k_rope(__hip_bfloat16* __restrict__ qkv,
                                              const float* __restrict__ cosT,
                                              const float* __restrict__ sinT) {
  int t = blockIdx.x * 256 + threadIdx.x;  // < 2*2048*16*64
  int i = t & 63;
  int h = (t >> 6) & 15;
  int s = (t >> 10) & 2047;
  int b = t >> 21;
  float c = cosT[s * 64 + i], si = sinT[s * 64 + i];
  size_t base = (size_t)(b * 2048 + s) * 6144 + h * 128;
#pragma unroll
  for (int part = 0; part < 2; ++part) {
    __hip_bfloat16* p = qkv + base + part * 2048;
    float t1 = __bfloat162float(p[i]);
    float t2 = __bfloat162float(p[i + 64]);
    p[i] = __float2bfloat16(t1 * c - t2 * si);
    p[i + 64] = __float2bfloat16(t1 * si + t2 * c);
  }
}

// -------------------------------------- V: [b,s,h,d] slice of qkv -> [b,h,d,s]
__global__ void k_vtrans(const __hip_bfloat16* __restrict__ qkv,
                         __hip_bfloat16* __restrict__ vT) {
  __shared__ __hip_bfloat16 tile[32][33];
  int s0 = blockIdx.x * 32, d0 = blockIdx.y * 32, bh = blockIdx.z;
  int b = bh >> 4, h = bh & 15;
  int tx = threadIdx.x, ty = threadIdx.y;
#pragma unroll
  for (int j = 0; j < 4; ++j)
    tile[ty + j * 8][tx] =
        qkv[(size_t)(b * 2048 + s0 + ty + j * 8) * 6144 + 4096 + h * 128 + d0 + tx];
  __syncthreads();
#pragma unroll
  for (int j = 0; j < 4; ++j)
    vT[(size_t)(bh * 128 + d0 + ty + j * 8) * 2048 + s0 + tx] = tile[tx][ty + j * 8];
}

// --------------------------------------------------------------- GEMM (A @ BT^T)
// A: MxK bf16 row-major; BT: NxK bf16 row-major; C = A*B + bias
// 128x128 tile, BK=64, 4 waves (2x2 of 64x64). XOR-swizzled LDS (16B units).
__global__ __launch_bounds__(256) void k_gemm_bt(
    const __hip_bfloat16* __restrict__ A, const __hip_bfloat16* __restrict__ BT,
    const float* __restrict__ bias, void* __restrict__ Cp, int M, int N, int K,
    int out_bf16) {
  __shared__ __align__(16) __hip_bfloat16 As[128 * 64];
  __shared__ __align__(16) __hip_bfloat16 Bs[128 * 64];
  const int tid = threadIdx.x;
  const int m0 = blockIdx.y * 128, n0 = blockIdx.x * 128;
  const int lane = tid & 63, w = tid >> 6;
  const int lr = lane & 15, lg = lane >> 4;
  const int wr = w >> 1, wc = w & 1;

  fx4 acc[4][4];
#pragma unroll
  for (int m = 0; m < 4; ++m)
#pragma unroll
    for (int n = 0; n < 4; ++n) acc[m][n] = (fx4)(0.0f);

  for (int kt = 0; kt < K; kt += 64) {
#pragma unroll
    for (int q = 0; q < 4; ++q) {
      const int slot = q * 256 + tid;
      const int row = slot >> 3, u = slot & 7;
      const int us = (u ^ (row & 7)) * 8;  // pre-swizzled source (involution)
      GLD16(&As[slot * 8], A + (size_t)(m0 + row) * K + kt + us);
      GLD16(&Bs[slot * 8], BT + (size_t)(n0 + row) * K + kt + us);
    }
    __syncthreads();  // drains vmcnt before barrier -> staged data visible
#pragma unroll
    for (int ks = 0; ks < 2; ++ks) {
      bx8 af[4], bf[4];
#pragma unroll
      for (int m = 0; m < 4; ++m) {
        const int r = wr * 64 + m * 16 + lr;
        const int u = ((ks * 4 + lg) ^ (lr & 7)) * 8;  // swizzled read
        af[m] = *(const bx8*)&As[r * 64 + u];
      }
#pragma unroll
      for (int n = 0; n < 4; ++n) {
        const int r = wc * 64 + n * 16 + lr;
        const int u = ((ks * 4 + lg) ^ (lr & 7)) * 8;
        bf[n] = *(const bx8*)&Bs[r * 64 + u];
      }
#pragma unroll
      for (int m = 0; m < 4; ++m)
#pragma unroll
        for (int n = 0; n < 4; ++n)
          acc[m][n] =
              __builtin_amdgcn_mfma_f32_16x16x32_bf16(af[m], bf[n], acc[m][n], 0, 0, 0);
    }
    __syncthreads();  // all waves done reading before next stage overwrites
  }

  float bv[4];
#pragma unroll
  for (int n = 0; n < 4; ++n) bv[n] = bias[n0 + wc * 64 + n * 16 + lr];

#pragma unroll
  for (int m = 0; m < 4; ++m)
#pragma unroll
    for (int n = 0; n < 4; ++n) {
      const int col = n0 + wc * 64 + n * 16 + lr;
#pragma unroll
      for (int j = 0; j < 4; ++j) {
        const int row = m0 + wr * 64 + m * 16 + lg * 4 + j;  // C/D: row=(lane>>4)*4+reg
        const float v = acc[m][n][j] + bv[n];
        if (out_bf16)
          ((__hip_bfloat16*)Cp)[(size_t)row * N + col] = __float2bfloat16(v);
        else
          ((float*)Cp)[(size_t)row * N + col] = v;
      }
    }
}

// ------------------------------------------------------------- flash attention
// grid: 1024 = (b:2)(h:16)(qt:32). block: 256 = 4 waves x 16 q-rows each.
#define ATT_SCALE 0.08838834764831845f  // 1/sqrt(128)

__global__ __launch_bounds__(256) void k_attn(const __hip_bfloat16* __restrict__ qkv,
                                              const __hip_bfloat16* __restrict__ vT,
                                              __hip_bfloat16* __restrict__ ctx) {
  __shared__ __align__(16) __hip_bfloat16 Ks[64 * 128];   // [kv][d], swizzled
  __shared__ __align__(16) __hip_bfloat16 Vs[128 * 64];   // [d][kv], swizzled
  __shared__ __align__(16) __hip_bfloat16 Ps[4 * 16 * 64];// per-wave P, swizzled
  const int tid = threadIdx.x;
  const int lane = tid & 63, w = tid >> 6;
  const int lr = lane & 15, lg = lane >> 4;
  const int bid = blockIdx.x;
  const int qt = bid & 31, h = (bid >> 5) & 15, b = bid >> 9;

  // Q fragments in registers (RoPE already applied)
  const int tq = qt * 64 + w * 16 + lr;
  const __hip_bfloat16* qrow = qkv + (size_t)(b * 2048 + tq) * 6144 + h * 128;
  bx8 qf[4];
#pragma unroll
  for (int ks = 0; ks < 4; ++ks) qf[ks] = *(const bx8*)(qrow + ks * 32 + lg * 8);

  float mrow[4], lrow[4];
  fx4 oacc[8];
#pragma unroll
  for (int j = 0; j < 4; ++j) { mrow[j] = -1e30f; lrow[j] = 0.0f; }
#pragma unroll
  for (int d = 0; d < 8; ++d) oacc[d] = (fx4)(0.0f);

  const int nkt = qt + 1;
  for (int kt = 0; kt < nkt; ++kt) {
    const int kv0 = kt * 64;
    __syncthreads();  // previous tile's LDS reads complete
#pragma unroll
    for (int q = 0; q < 4; ++q) {
      const int slot = q * 256 + tid;
      {  // K tile: row=kv (64 rows x 256B), 16 units/row
        const int row = slot >> 4, u = slot & 15;
        GLD16(&Ks[slot * 8], qkv + (size_t)(b * 2048 + kv0 + row) * 6144 + 2048 +
                                 h * 128 + ((u ^ (row & 15)) * 8));
      }
      {  // V^T tile: row=d (128 rows x 128B), 8 units/row
        const int d = slot >> 3, u = slot & 7;
        GLD16(&Vs[slot * 8], vT + (size_t)((b * 16 + h) * 128 + d) * 2048 + kv0 +
                                 ((u ^ (d & 7)) * 8));
      }
    }
    __syncthreads();  // staging complete (vmcnt drained)

    // ---- QK^T: S[t][kv], wave's 16 t-rows x 64 kv
    fx4 sacc[4];
#pragma unroll
    for (int n = 0; n < 4; ++n) sacc[n] = (fx4)(0.0f);
#pragma unroll
    for (int n = 0; n < 4; ++n) {
      const int r = n * 16 + lr;
#pragma unroll
      for (int ks = 0; ks < 4; ++ks) {
        const int u = ((ks * 4 + lg) ^ lr) * 8;
        const bx8 kf = *(const bx8*)&Ks[r * 128 + u];
        sacc[n] = __builtin_amdgcn_mfma_f32_16x16x32_bf16(qf[ks], kf, sacc[n], 0, 0, 0);
      }
    }

    // ---- online softmax (rows t = lg*4+j; reduce over 16 lanes = kv cols)
    float sc[4][4], pmax[4];
#pragma unroll
    for (int j = 0; j < 4; ++j) pmax[j] = -1e30f;
#pragma unroll
    for (int n = 0; n < 4; ++n) {
      const int kvi = kv0 + n * 16 + lr;
#pragma unroll
      for (int j = 0; j < 4; ++j) {
        const int qi = qt * 64 + w * 16 + lg * 4 + j;
        float v = sacc[n][j] * ATT_SCALE;
        if (kvi > qi) v = -1e30f;  // causal
        sc[n][j] = v;
        pmax[j] = fmaxf(pmax[j], v);
      }
    }
#pragma unroll
    for (int off = 1; off < 16; off <<= 1)
#pragma unroll
      for (int j = 0; j < 4; ++j) pmax[j] = fmaxf(pmax[j], __shfl_xor(pmax[j], off));

    float f[4], psum[4];
#pragma unroll
    for (int j = 0; j < 4; ++j) {
      const float mn = fmaxf(mrow[j], pmax[j]);
      f[j] = __expf(mrow[j] - mn);
      mrow[j] = mn;
      psum[j] = 0.0f;
    }
#pragma unroll
    for (int n = 0; n < 4; ++n)
#pragma unroll
      for (int j = 0; j < 4; ++j) {
        const float p = __expf(sc[n][j] - mrow[j]);
        psum[j] += p;
        sc[n][j] = p;
      }
#pragma unroll
    for (int off = 1; off < 16; off <<= 1)
#pragma unroll
      for (int j = 0; j < 4; ++j) psum[j] += __shfl_xor(psum[j], off);
#pragma unroll
    for (int j = 0; j < 4; ++j) lrow[j] = lrow[j] * f[j] + psum[j];
#pragma unroll
    for (int d = 0; d < 8; ++d)
#pragma unroll
      for (int j = 0; j < 4; ++j) oacc[d][j] *= f[j];

    // ---- P -> LDS (bf16, swizzled in 8-elem units)
#pragma unroll
    for (int n = 0; n < 4; ++n)
#pragma unroll
      for (int j = 0; j < 4; ++j) {
        const int r = lg * 4 + j, c = n * 16 + lr;
        const int c2 = (c & 7) | (((c >> 3) ^ (r & 7)) << 3);
        Ps[w * 1024 + r * 64 + c2] = __float2bfloat16(sc[n][j]);
      }
    __syncthreads();  // P visible (and lgkm drained)

    // ---- PV: O[t][d] += P[t][kv] * V[kv][d]
#pragma unroll
    for (int ks2 = 0; ks2 < 2; ++ks2) {
      const int u = ((ks2 * 4 + lg) ^ (lr & 7)) * 8;
      const bx8 pf = *(const bx8*)&Ps[w * 1024 + lr * 64 + u];
#pragma unroll
      for (int dn = 0; dn < 8; ++dn) {
        const int d = dn * 16 + lr;
        const bx8 vf = *(const bx8*)&Vs[d * 64 + u];
        oacc[dn] = __builtin_amdgcn_mfma_f32_16x16x32_bf16(pf, vf, oacc[dn], 0, 0, 0);
      }
    }
  }

  // ---- write ctx [b,s, h*128+d] bf16
#pragma unroll
  for (int dn = 0; dn < 8; ++dn)
#pragma unroll
    for (int j = 0; j < 4; ++j) {
      const int tg = qt * 64 + w * 16 + lg * 4 + j;
      const float ov = oacc[dn][j] / lrow[j];
      ctx[(size_t)(b * 2048 + tg) * 2048 + h * 128 + dn * 16 + lr] =
          __float2bfloat16(ov);
    }
}

// ------------------------------------------------------------------- launcher
extern "C" void kernel_launch(void* const* d_in, const int* in_sizes, int n_in,
                              void* d_out, int out_size, void* d_ws, size_t ws_size,
                              hipStream_t stream) {
  const float* x = (const float*)d_in[0];
  const float* Wqkv = (const float*)d_in[1];
  const float* bqkv = (const float*)d_in[2];
  const float* Wout = (const float*)d_in[3];
  const float* bout = (const float*)d_in[4];
  float* out = (float*)d_out;

  char* ws = (char*)d_ws;
  __hip_bfloat16* xb    = (__hip_bfloat16*)(ws + 0);          // 16 MiB
  __hip_bfloat16* wqkvT = (__hip_bfloat16*)(ws + 16777216);   // 24 MiB
  __hip_bfloat16* woutT = (__hip_bfloat16*)(ws + 41943040);   // 8 MiB
  __hip_bfloat16* qkvb  = (__hip_bfloat16*)(ws + 50331648);   // 48 MiB
  __hip_bfloat16* vTb   = (__hip_bfloat16*)(ws + 100663296);  // 16 MiB
  __hip_bfloat16* ctxb  = (__hip_bfloat16*)(ws + 117440512);  // 16 MiB
  float* cosT = (float*)(ws + 134217728);                     // 512 KiB
  float* sinT = (float*)(ws + 134742016);                     // 512 KiB

  // 1) casts / transposes / tables
  k_cast<<<8192, 256, 0, stream>>>(x, xb, 2097152);
  k_tcast<<<dim3(192, 64), dim3(32, 8), 0, stream>>>(Wqkv, wqkvT, 2048, 6144);
  k_tcast<<<dim3(64, 64), dim3(32, 8), 0, stream>>>(Wout, woutT, 2048, 2048);
  k_ropetab<<<512, 256, 0, stream>>>(cosT, sinT);
  // 2) QKV = x @ Wqkv + b  (bf16 out)
  k_gemm_bt<<<dim3(48, 32), 256, 0, stream>>>(xb, wqkvT, bqkv, qkvb, 4096, 6144,
                                              2048, 1);
  // 3) RoPE on q,k
  k_rope<<<16384, 256, 0, stream>>>(qkvb, cosT, sinT);
  // 4) V transpose for PV operand
  k_vtrans<<<dim3(64, 4, 32), dim3(32, 8), 0, stream>>>(qkvb, vTb);
  // 5) causal flash attention
  k_attn<<<1024, 256, 0, stream>>>(qkvb, vTb, ctxb);
  // 6) out = ctx @ Wout + bout (fp32 out)
  k_gemm_bt<<<dim3(16, 32), 256, 0, stream>>>(ctxb, woutT, bout, out, 4096, 2048,
                                              2048, 0);
}

// Round 2
// 340.778 us; speedup vs baseline: 1.1325x; 1.1325x over previous
//
#include <hip/hip_runtime.h>
#include <hip/hip_bf16.h>

typedef __attribute__((ext_vector_type(4))) float fx4;
typedef __attribute__((ext_vector_type(8))) short bx8;

#define GLD16(dst, src)                                                        \
  __builtin_amdgcn_global_load_lds(                                            \
      (__attribute__((address_space(1))) void*)(src),                          \
      (__attribute__((address_space(3))) void*)(dst), 16, 0, 0)

__device__ inline float bf2f(short s_) {
  unsigned int u = ((unsigned int)(unsigned short)s_) << 16;
  float f;
  __builtin_memcpy(&f, &u, 4);
  return f;
}
__device__ inline short f2bf(float f) {
  __hip_bfloat16 h = __float2bfloat16(f);
  short r;
  __builtin_memcpy(&r, &h, 2);
  return r;
}

// ---------------------------------------------------------------- cast x->bf16
__global__ __launch_bounds__(256) void k_cast(const float* __restrict__ in,
                                              __hip_bfloat16* __restrict__ out,
                                              int n4) {
  int i = blockIdx.x * 256 + threadIdx.x;
  if (i >= n4) return;
  float4 v = reinterpret_cast<const float4*>(in)[i];
  __hip_bfloat16 t[4] = {__float2bfloat16(v.x), __float2bfloat16(v.y),
                         __float2bfloat16(v.z), __float2bfloat16(v.w)};
  reinterpret_cast<ushort4*>(out)[i] = *reinterpret_cast<ushort4*>(t);
}

// ------------------------------------------- transpose-cast fp32 RxC -> bf16 CxR
__global__ void k_tcast(const float* __restrict__ in,
                        __hip_bfloat16* __restrict__ out, int R, int C) {
  __shared__ float tile[32][33];
  int c0 = blockIdx.x * 32, r0 = blockIdx.y * 32;
  int tx = threadIdx.x, ty = threadIdx.y;
#pragma unroll
  for (int j = 0; j < 4; ++j)
    tile[ty + j * 8][tx] = in[(size_t)(r0 + ty + j * 8) * C + c0 + tx];
  __syncthreads();
#pragma unroll
  for (int j = 0; j < 4; ++j)
    out[(size_t)(c0 + ty + j * 8) * R + r0 + tx] =
        __float2bfloat16(tile[tx][ty + j * 8]);
}

// ----------------------------------------------------------- rope cos/sin table
__global__ __launch_bounds__(256) void k_ropetab(float* __restrict__ cosT,
                                                 float* __restrict__ sinT) {
  int idx = blockIdx.x * 256 + threadIdx.x;  // 2048*64
  int t = idx >> 6, i = idx & 63;
  float inv = expf(-logf(10000.0f) * (float)i * (1.0f / 64.0f));
  float fr = (float)t * inv;
  cosT[idx] = cosf(fr);
  sinT[idx] = sinf(fr);
}

// ---------------------------- apply rope to q,k in place (vectorized, 8 d/thread)
__global__ __launch_bounds__(256) void k_rope(__hip_bfloat16* __restrict__ qkv,
                                              const float* __restrict__ cosT,
                                              const float* __restrict__ sinT) {
  int t = blockIdx.x * 256 + threadIdx.x;  // 2^20 threads
  int d0 = (t & 7) * 8;
  int qk = (t >> 3) & 1;
  int h = (t >> 4) & 15;
  int s = (t >> 8) & 2047;
  int b = (t >> 19) & 1;
  __hip_bfloat16* base =
      qkv + (size_t)(b * 2048 + s) * 6144 + qk * 2048 + h * 128;
  bx8 lo = *(const bx8*)(base + d0);
  bx8 hi = *(const bx8*)(base + 64 + d0);
  float4 ca = *(const float4*)&cosT[s * 64 + d0];
  float4 cb = *(const float4*)&cosT[s * 64 + d0 + 4];
  float4 sa = *(const float4*)&sinT[s * 64 + d0];
  float4 sb = *(const float4*)&sinT[s * 64 + d0 + 4];
  float c[8] = {ca.x, ca.y, ca.z, ca.w, cb.x, cb.y, cb.z, cb.w};
  float si[8] = {sa.x, sa.y, sa.z, sa.w, sb.x, sb.y, sb.z, sb.w};
  bx8 olo, ohi;
#pragma unroll
  for (int e = 0; e < 8; ++e) {
    float t1 = bf2f(lo[e]), t2 = bf2f(hi[e]);
    olo[e] = f2bf(t1 * c[e] - t2 * si[e]);
    ohi[e] = f2bf(t1 * si[e] + t2 * c[e]);
  }
  *(bx8*)(base + d0) = olo;
  *(bx8*)(base + 64 + d0) = ohi;
}

// -------------------------------------- V: [b,s,h,d] slice of qkv -> [b,h,d,s]
__global__ void k_vtrans(const __hip_bfloat16* __restrict__ qkv,
                         __hip_bfloat16* __restrict__ vT) {
  __shared__ __hip_bfloat16 tile[32][33];
  int s0 = blockIdx.x * 32, d0 = blockIdx.y * 32, bh = blockIdx.z;
  int b = bh >> 4, h = bh & 15;
  int tx = threadIdx.x, ty = threadIdx.y;
#pragma unroll
  for (int j = 0; j < 4; ++j)
    tile[ty + j * 8][tx] =
        qkv[(size_t)(b * 2048 + s0 + ty + j * 8) * 6144 + 4096 + h * 128 + d0 + tx];
  __syncthreads();
#pragma unroll
  for (int j = 0; j < 4; ++j)
    vT[(size_t)(bh * 128 + d0 + ty + j * 8) * 2048 + s0 + tx] = tile[tx][ty + j * 8];
}

// --------------------------------------------------------------- GEMM (A @ BT^T)
__global__ __launch_bounds__(256) void k_gemm_bt(
    const __hip_bfloat16* __restrict__ A, const __hip_bfloat16* __restrict__ BT,
    const float* __restrict__ bias, void* __restrict__ Cp, int M, int N, int K,
    int out_bf16) {
  __shared__ __align__(16) __hip_bfloat16 As[128 * 64];
  __shared__ __align__(16) __hip_bfloat16 Bs[128 * 64];
  const int tid = threadIdx.x;
  const int m0 = blockIdx.y * 128, n0 = blockIdx.x * 128;
  const int lane = tid & 63, w = tid >> 6;
  const int lr = lane & 15, lg = lane >> 4;
  const int wr = w >> 1, wc = w & 1;

  fx4 acc[4][4];
#pragma unroll
  for (int m = 0; m < 4; ++m)
#pragma unroll
    for (int n = 0; n < 4; ++n) acc[m][n] = (fx4)(0.0f);

  for (int kt = 0; kt < K; kt += 64) {
#pragma unroll
    for (int q = 0; q < 4; ++q) {
      const int slot = q * 256 + tid;
      const int row = slot >> 3, u = slot & 7;
      const int us = (u ^ (row & 7)) * 8;
      GLD16(&As[slot * 8], A + (size_t)(m0 + row) * K + kt + us);
      GLD16(&Bs[slot * 8], BT + (size_t)(n0 + row) * K + kt + us);
    }
    __syncthreads();
#pragma unroll
    for (int ks = 0; ks < 2; ++ks) {
      bx8 af[4], bf[4];
#pragma unroll
      for (int m = 0; m < 4; ++m) {
        const int r = wr * 64 + m * 16 + lr;
        const int u = ((ks * 4 + lg) ^ (lr & 7)) * 8;
        af[m] = *(const bx8*)&As[r * 64 + u];
      }
#pragma unroll
      for (int n = 0; n < 4; ++n) {
        const int r = wc * 64 + n * 16 + lr;
        const int u = ((ks * 4 + lg) ^ (lr & 7)) * 8;
        bf[n] = *(const bx8*)&Bs[r * 64 + u];
      }
#pragma unroll
      for (int m = 0; m < 4; ++m)
#pragma unroll
        for (int n = 0; n < 4; ++n)
          acc[m][n] =
              __builtin_amdgcn_mfma_f32_16x16x32_bf16(af[m], bf[n], acc[m][n], 0, 0, 0);
    }
    __syncthreads();
  }

  float bv[4];
#pragma unroll
  for (int n = 0; n < 4; ++n) bv[n] = bias[n0 + wc * 64 + n * 16 + lr];

#pragma unroll
  for (int m = 0; m < 4; ++m)
#pragma unroll
    for (int n = 0; n < 4; ++n) {
      const int col = n0 + wc * 64 + n * 16 + lr;
#pragma unroll
      for (int j = 0; j < 4; ++j) {
        const int row = m0 + wr * 64 + m * 16 + lg * 4 + j;
        const float v = acc[m][n][j] + bv[n];
        if (out_bf16)
          ((__hip_bfloat16*)Cp)[(size_t)row * N + col] = __float2bfloat16(v);
        else
          ((float*)Cp)[(size_t)row * N + col] = v;
      }
    }
}

// ------------------------------------------------------------- flash attention
// QBLK=128 (4 waves x 32 rows), KVBLK=64, double-buffered K/V, counted vmcnt.
// grid 512: lo=bid&255, hi=bid>>8; bh=lo&31; qsel=lo>>5; qt = hi? qsel : 15-qsel
// => CU pairing (bid, bid+256) has constant total work (34 kv-tiles).
#define ATT_SL2E 0.12751740f  // (1/sqrt(128)) * log2(e)

__global__ __launch_bounds__(256, 2) void k_attn(
    const __hip_bfloat16* __restrict__ qkv, const __hip_bfloat16* __restrict__ vT,
    __hip_bfloat16* __restrict__ ctx) {
  __shared__ __align__(16) __hip_bfloat16 Ks[2][64 * 128];
  __shared__ __align__(16) __hip_bfloat16 Vs[2][128 * 64];
  __shared__ __align__(16) __hip_bfloat16 Ps[4][32 * 64];
  const int tid = threadIdx.x;
  const int lane = tid & 63, w = tid >> 6;
  const int lr = lane & 15, lg = lane >> 4;
  const int bid = blockIdx.x;
  const int lo = bid & 255, hi = bid >> 8;
  const int bh = lo & 31, qsel = lo >> 5;
  const int b = bh >> 4, h = bh & 15;
  const int qt = hi ? qsel : 15 - qsel;

  const __hip_bfloat16* kbase = qkv + (size_t)b * 2048 * 6144 + 2048 + h * 128;
  const __hip_bfloat16* vbase = vT + (size_t)(b * 16 + h) * 128 * 2048;

  auto STAGE = [&](int bufi, int kt) {
    const int kv0 = kt * 64;
#pragma unroll
    for (int q = 0; q < 4; ++q) {
      const int slot = q * 256 + tid;
      {
        const int row = slot >> 4, u = slot & 15;
        GLD16(&Ks[bufi][slot * 8],
              kbase + (size_t)(kv0 + row) * 6144 + ((u ^ (row & 15)) * 8));
      }
      {
        const int d = slot >> 3, u = slot & 7;
        GLD16(&Vs[bufi][slot * 8],
              vbase + (size_t)d * 2048 + kv0 + ((u ^ (d & 7)) * 8));
      }
    }
  };

  // Q fragments: 32 rows/wave, rows w*32 + m*16 + lr
  const __hip_bfloat16* qbase =
      qkv + (size_t)(b * 2048 + qt * 128 + w * 32) * 6144 + h * 128;
  bx8 qf[2][4];
#pragma unroll
  for (int m = 0; m < 2; ++m)
#pragma unroll
    for (int ks = 0; ks < 4; ++ks)
      qf[m][ks] = *(const bx8*)(qbase + (size_t)(m * 16 + lr) * 6144 + ks * 32 + lg * 8);

  float mrow[2][4], lrow[2][4];
  fx4 oacc[2][8];
#pragma unroll
  for (int m = 0; m < 2; ++m)
#pragma unroll
    for (int j = 0; j < 4; ++j) {
      mrow[m][j] = -3e38f;
      lrow[m][j] = 0.0f;
    }
#pragma unroll
  for (int m = 0; m < 2; ++m)
#pragma unroll
    for (int d = 0; d < 8; ++d) oacc[m][d] = (fx4)(0.0f);

  const int nkt = 2 * qt + 2;
  const int qrow0 = qt * 128 + w * 32;

  STAGE(0, 0);
  for (int kt = 0; kt < nkt; ++kt) {
    const int cur = kt & 1;
    if (kt + 1 < nkt) {
      STAGE(cur ^ 1, kt + 1);
      asm volatile("s_waitcnt vmcnt(8)" ::: "memory");
    } else {
      asm volatile("s_waitcnt vmcnt(0)" ::: "memory");
    }
    __builtin_amdgcn_s_barrier();
    asm volatile("" ::: "memory");

    // ---- QK^T: rows (2x16 per wave) x 64 kv
    fx4 sacc[2][4];
#pragma unroll
    for (int n = 0; n < 4; ++n) {
      sacc[0][n] = (fx4)(0.0f);
      sacc[1][n] = (fx4)(0.0f);
    }
    __builtin_amdgcn_s_setprio(1);
#pragma unroll
    for (int n = 0; n < 4; ++n) {
      const int r = n * 16 + lr;
#pragma unroll
      for (int ks = 0; ks < 4; ++ks) {
        const bx8 kf = *(const bx8*)&Ks[cur][r * 128 + (((ks * 4 + lg) ^ lr) * 8)];
        sacc[0][n] =
            __builtin_amdgcn_mfma_f32_16x16x32_bf16(qf[0][ks], kf, sacc[0][n], 0, 0, 0);
        sacc[1][n] =
            __builtin_amdgcn_mfma_f32_16x16x32_bf16(qf[1][ks], kf, sacc[1][n], 0, 0, 0);
      }
    }
    __builtin_amdgcn_s_setprio(0);

    // ---- online softmax (log2 domain), mask only near-diagonal tiles
    const int kv0 = kt * 64;
    float sc[2][4][4], pmax[2][4];
#pragma unroll
    for (int m = 0; m < 2; ++m)
#pragma unroll
      for (int j = 0; j < 4; ++j) pmax[m][j] = -3e38f;

    const bool needmask = (kv0 + 63) > qrow0;  // wave-uniform
    if (needmask) {
#pragma unroll
      for (int n = 0; n < 4; ++n) {
        const int kvi = kv0 + n * 16 + lr;
#pragma unroll
        for (int m = 0; m < 2; ++m)
#pragma unroll
          for (int j = 0; j < 4; ++j) {
            const int qi = qrow0 + m * 16 + lg * 4 + j;
            float v = sacc[m][n][j] * ATT_SL2E;
            if (kvi > qi) v = -3e38f;
            sc[m][n][j] = v;
            pmax[m][j] = fmaxf(pmax[m][j], v);
          }
      }
    } else {
#pragma unroll
      for (int n = 0; n < 4; ++n)
#pragma unroll
        for (int m = 0; m < 2; ++m)
#pragma unroll
          for (int j = 0; j < 4; ++j) {
            float v = sacc[m][n][j] * ATT_SL2E;
            sc[m][n][j] = v;
            pmax[m][j] = fmaxf(pmax[m][j], v);
          }
    }
#pragma unroll
    for (int off = 1; off < 16; off <<= 1)
#pragma unroll
      for (int m = 0; m < 2; ++m)
#pragma unroll
        for (int j = 0; j < 4; ++j)
          pmax[m][j] = fmaxf(pmax[m][j], __shfl_xor(pmax[m][j], off));

    // defer-max: skip rescale if max didn't grow past 2^8
    bool ok = true;
#pragma unroll
    for (int m = 0; m < 2; ++m)
#pragma unroll
      for (int j = 0; j < 4; ++j) ok &= (pmax[m][j] <= mrow[m][j] + 8.0f);
    if (!__all(ok)) {
#pragma unroll
      for (int m = 0; m < 2; ++m)
#pragma unroll
        for (int j = 0; j < 4; ++j) {
          const float mn = fmaxf(mrow[m][j], pmax[m][j]);
          const float f = exp2f(mrow[m][j] - mn);
          mrow[m][j] = mn;
          lrow[m][j] *= f;
#pragma unroll
          for (int d = 0; d < 8; ++d) oacc[m][d][j] *= f;
        }
    }

    float psum[2][4];
#pragma unroll
    for (int m = 0; m < 2; ++m)
#pragma unroll
      for (int j = 0; j < 4; ++j) psum[m][j] = 0.0f;
#pragma unroll
    for (int n = 0; n < 4; ++n)
#pragma unroll
      for (int m = 0; m < 2; ++m)
#pragma unroll
        for (int j = 0; j < 4; ++j) {
          const float p = exp2f(sc[m][n][j] - mrow[m][j]);
          sc[m][n][j] = p;
          psum[m][j] += p;
        }
#pragma unroll
    for (int off = 1; off < 16; off <<= 1)
#pragma unroll
      for (int m = 0; m < 2; ++m)
#pragma unroll
        for (int j = 0; j < 4; ++j) psum[m][j] += __shfl_xor(psum[m][j], off);
#pragma unroll
    for (int m = 0; m < 2; ++m)
#pragma unroll
      for (int j = 0; j < 4; ++j) lrow[m][j] += psum[m][j];

    // ---- P -> LDS (wave-private, swizzled)
#pragma unroll
    for (int m = 0; m < 2; ++m)
#pragma unroll
      for (int n = 0; n < 4; ++n)
#pragma unroll
        for (int j = 0; j < 4; ++j) {
          const int r = m * 16 + lg * 4 + j, c = n * 16 + lr;
          const int c2 = (c & 7) | (((c >> 3) ^ (r & 7)) << 3);
          Ps[w][r * 64 + c2] = __float2bfloat16(sc[m][n][j]);
        }

    // ---- PV: O[r][d] += P[r][kv] * V[kv][d]
    __builtin_amdgcn_s_setprio(1);
#pragma unroll
    for (int ks2 = 0; ks2 < 2; ++ks2) {
      const int u = ((ks2 * 4 + lg) ^ (lr & 7)) * 8;
      const bx8 pf0 = *(const bx8*)&Ps[w][(0 * 16 + lr) * 64 + u];
      const bx8 pf1 = *(const bx8*)&Ps[w][(1 * 16 + lr) * 64 + u];
#pragma unroll
      for (int dn = 0; dn < 8; ++dn) {
        const bx8 vf = *(const bx8*)&Vs[cur][(dn * 16 + lr) * 64 + u];
        oacc[0][dn] =
            __builtin_amdgcn_mfma_f32_16x16x32_bf16(pf0, vf, oacc[0][dn], 0, 0, 0);
        oacc[1][dn] =
            __builtin_amdgcn_mfma_f32_16x16x32_bf16(pf1, vf, oacc[1][dn], 0, 0, 0);
      }
    }
    __builtin_amdgcn_s_setprio(0);
    __builtin_amdgcn_s_barrier();  // all waves done reading buf[cur]
    asm volatile("" ::: "memory");
  }

  // ---- output
  float rl[2][4];
#pragma unroll
  for (int m = 0; m < 2; ++m)
#pragma unroll
    for (int j = 0; j < 4; ++j) rl[m][j] = 1.0f / lrow[m][j];
#pragma unroll
  for (int m = 0; m < 2; ++m)
#pragma unroll
    for (int dn = 0; dn < 8; ++dn)
#pragma unroll
      for (int j = 0; j < 4; ++j) {
        const int row = qt * 128 + w * 32 + m * 16 + lg * 4 + j;
        ctx[(size_t)(b * 2048 + row) * 2048 + h * 128 + dn * 16 + lr] =
            __float2bfloat16(oacc[m][dn][j] * rl[m][j]);
      }
}

// ------------------------------------------------------------------- launcher
extern "C" void kernel_launch(void* const* d_in, const int* in_sizes, int n_in,
                              void* d_out, int out_size, void* d_ws, size_t ws_size,
                              hipStream_t stream) {
  const float* x = (const float*)d_in[0];
  const float* Wqkv = (const float*)d_in[1];
  const float* bqkv = (const float*)d_in[2];
  const float* Wout = (const float*)d_in[3];
  const float* bout = (const float*)d_in[4];
  float* out = (float*)d_out;

  char* ws = (char*)d_ws;
  __hip_bfloat16* xb    = (__hip_bfloat16*)(ws + 0);          // 16 MiB
  __hip_bfloat16* wqkvT = (__hip_bfloat16*)(ws + 16777216);   // 24 MiB
  __hip_bfloat16* woutT = (__hip_bfloat16*)(ws + 41943040);   // 8 MiB
  __hip_bfloat16* qkvb  = (__hip_bfloat16*)(ws + 50331648);   // 48 MiB
  __hip_bfloat16* vTb   = (__hip_bfloat16*)(ws + 100663296);  // 16 MiB
  __hip_bfloat16* ctxb  = (__hip_bfloat16*)(ws + 117440512);  // 16 MiB
  float* cosT = (float*)(ws + 134217728);                     // 512 KiB
  float* sinT = (float*)(ws + 134742016);                     // 512 KiB

  k_cast<<<8192, 256, 0, stream>>>(x, xb, 2097152);
  k_tcast<<<dim3(192, 64), dim3(32, 8), 0, stream>>>(Wqkv, wqkvT, 2048, 6144);
  k_tcast<<<dim3(64, 64), dim3(32, 8), 0, stream>>>(Wout, woutT, 2048, 2048);
  k_ropetab<<<512, 256, 0, stream>>>(cosT, sinT);
  k_gemm_bt<<<dim3(48, 32), 256, 0, stream>>>(xb, wqkvT, bqkv, qkvb, 4096, 6144,
                                              2048, 1);
  k_rope<<<4096, 256, 0, stream>>>(qkvb, cosT, sinT);
  k_vtrans<<<dim3(64, 4, 32), dim3(32, 8), 0, stream>>>(qkvb, vTb);
  k_attn<<<512, 256, 0, stream>>>(qkvb, vTb, ctxb);
  k_gemm_bt<<<dim3(16, 32), 256, 0, stream>>>(ctxb, woutT, bout, out, 4096, 2048,
                                              2048, 0);
}

// Round 3
// 331.214 us; speedup vs baseline: 1.1652x; 1.0289x over previous
//
#include <hip/hip_runtime.h>
#include <hip/hip_bf16.h>

typedef __attribute__((ext_vector_type(4))) float fx4;
typedef __attribute__((ext_vector_type(8))) short bx8;

#define GLD16(dst, src)                                                        \
  __builtin_amdgcn_global_load_lds(                                            \
      (__attribute__((address_space(1))) void*)(src),                          \
      (__attribute__((address_space(3))) void*)(dst), 16, 0, 0)

__device__ inline float bf2f(short s_) {
  unsigned int u = ((unsigned int)(unsigned short)s_) << 16;
  float f;
  __builtin_memcpy(&f, &u, 4);
  return f;
}
__device__ inline short f2bf(float f) {
  __hip_bfloat16 h = __float2bfloat16(f);
  short r;
  __builtin_memcpy(&r, &h, 2);
  return r;
}

// ---------------------------------------------------------------- cast x->bf16
__global__ __launch_bounds__(256) void k_cast(const float* __restrict__ in,
                                              __hip_bfloat16* __restrict__ out,
                                              int n4) {
  int i = blockIdx.x * 256 + threadIdx.x;
  if (i >= n4) return;
  float4 v = reinterpret_cast<const float4*>(in)[i];
  __hip_bfloat16 t[4] = {__float2bfloat16(v.x), __float2bfloat16(v.y),
                         __float2bfloat16(v.z), __float2bfloat16(v.w)};
  reinterpret_cast<ushort4*>(out)[i] = *reinterpret_cast<ushort4*>(t);
}

// ------------------------------------------- transpose-cast fp32 RxC -> bf16 CxR
__global__ void k_tcast(const float* __restrict__ in,
                        __hip_bfloat16* __restrict__ out, int R, int C) {
  __shared__ float tile[32][33];
  int c0 = blockIdx.x * 32, r0 = blockIdx.y * 32;
  int tx = threadIdx.x, ty = threadIdx.y;
#pragma unroll
  for (int j = 0; j < 4; ++j)
    tile[ty + j * 8][tx] = in[(size_t)(r0 + ty + j * 8) * C + c0 + tx];
  __syncthreads();
#pragma unroll
  for (int j = 0; j < 4; ++j)
    out[(size_t)(c0 + ty + j * 8) * R + r0 + tx] =
        __float2bfloat16(tile[tx][ty + j * 8]);
}

// ----------------------------------------------------------- rope cos/sin table
__global__ __launch_bounds__(256) void k_ropetab(float* __restrict__ cosT,
                                                 float* __restrict__ sinT) {
  int idx = blockIdx.x * 256 + threadIdx.x;  // 2048*64
  int t = idx >> 6, i = idx & 63;
  float inv = expf(-logf(10000.0f) * (float)i * (1.0f / 64.0f));
  float fr = (float)t * inv;
  cosT[idx] = cosf(fr);
  sinT[idx] = sinf(fr);
}

// ---------------------------- apply rope to q,k in place (vectorized, 8 d/thread)
__global__ __launch_bounds__(256) void k_rope(__hip_bfloat16* __restrict__ qkv,
                                              const float* __restrict__ cosT,
                                              const float* __restrict__ sinT) {
  int t = blockIdx.x * 256 + threadIdx.x;  // 2^20 threads
  int d0 = (t & 7) * 8;
  int qk = (t >> 3) & 1;
  int h = (t >> 4) & 15;
  int s = (t >> 8) & 2047;
  int b = (t >> 19) & 1;
  __hip_bfloat16* base =
      qkv + (size_t)(b * 2048 + s) * 6144 + qk * 2048 + h * 128;
  bx8 lo = *(const bx8*)(base + d0);
  bx8 hi = *(const bx8*)(base + 64 + d0);
  float4 ca = *(const float4*)&cosT[s * 64 + d0];
  float4 cb = *(const float4*)&cosT[s * 64 + d0 + 4];
  float4 sa = *(const float4*)&sinT[s * 64 + d0];
  float4 sb = *(const float4*)&sinT[s * 64 + d0 + 4];
  float c[8] = {ca.x, ca.y, ca.z, ca.w, cb.x, cb.y, cb.z, cb.w};
  float si[8] = {sa.x, sa.y, sa.z, sa.w, sb.x, sb.y, sb.z, sb.w};
  bx8 olo, ohi;
#pragma unroll
  for (int e = 0; e < 8; ++e) {
    float t1 = bf2f(lo[e]), t2 = bf2f(hi[e]);
    olo[e] = f2bf(t1 * c[e] - t2 * si[e]);
    ohi[e] = f2bf(t1 * si[e] + t2 * c[e]);
  }
  *(bx8*)(base + d0) = olo;
  *(bx8*)(base + 64 + d0) = ohi;
}

// -------------------------------------- V: [b,s,h,d] slice of qkv -> [b,h,d,s]
__global__ void k_vtrans(const __hip_bfloat16* __restrict__ qkv,
                         __hip_bfloat16* __restrict__ vT) {
  __shared__ __hip_bfloat16 tile[32][33];
  int s0 = blockIdx.x * 32, d0 = blockIdx.y * 32, bh = blockIdx.z;
  int b = bh >> 4, h = bh & 15;
  int tx = threadIdx.x, ty = threadIdx.y;
#pragma unroll
  for (int j = 0; j < 4; ++j)
    tile[ty + j * 8][tx] =
        qkv[(size_t)(b * 2048 + s0 + ty + j * 8) * 6144 + 4096 + h * 128 + d0 + tx];
  __syncthreads();
#pragma unroll
  for (int j = 0; j < 4; ++j)
    vT[(size_t)(bh * 128 + d0 + ty + j * 8) * 2048 + s0 + tx] = tile[tx][ty + j * 8];
}

// --------------------------------------------------------------- GEMM (A @ BT^T)
__global__ __launch_bounds__(256) void k_gemm_bt(
    const __hip_bfloat16* __restrict__ A, const __hip_bfloat16* __restrict__ BT,
    const float* __restrict__ bias, void* __restrict__ Cp, int M, int N, int K,
    int out_bf16) {
  __shared__ __align__(16) __hip_bfloat16 As[128 * 64];
  __shared__ __align__(16) __hip_bfloat16 Bs[128 * 64];
  const int tid = threadIdx.x;
  const int m0 = blockIdx.y * 128, n0 = blockIdx.x * 128;
  const int lane = tid & 63, w = tid >> 6;
  const int lr = lane & 15, lg = lane >> 4;
  const int wr = w >> 1, wc = w & 1;

  fx4 acc[4][4];
#pragma unroll
  for (int m = 0; m < 4; ++m)
#pragma unroll
    for (int n = 0; n < 4; ++n) acc[m][n] = (fx4)(0.0f);

  for (int kt = 0; kt < K; kt += 64) {
#pragma unroll
    for (int q = 0; q < 4; ++q) {
      const int slot = q * 256 + tid;
      const int row = slot >> 3, u = slot & 7;
      const int us = (u ^ (row & 7)) * 8;
      GLD16(&As[slot * 8], A + (size_t)(m0 + row) * K + kt + us);
      GLD16(&Bs[slot * 8], BT + (size_t)(n0 + row) * K + kt + us);
    }
    __syncthreads();
#pragma unroll
    for (int ks = 0; ks < 2; ++ks) {
      bx8 af[4], bf[4];
#pragma unroll
      for (int m = 0; m < 4; ++m) {
        const int r = wr * 64 + m * 16 + lr;
        const int u = ((ks * 4 + lg) ^ (lr & 7)) * 8;
        af[m] = *(const bx8*)&As[r * 64 + u];
      }
#pragma unroll
      for (int n = 0; n < 4; ++n) {
        const int r = wc * 64 + n * 16 + lr;
        const int u = ((ks * 4 + lg) ^ (lr & 7)) * 8;
        bf[n] = *(const bx8*)&Bs[r * 64 + u];
      }
#pragma unroll
      for (int m = 0; m < 4; ++m)
#pragma unroll
        for (int n = 0; n < 4; ++n)
          acc[m][n] =
              __builtin_amdgcn_mfma_f32_16x16x32_bf16(af[m], bf[n], acc[m][n], 0, 0, 0);
    }
    __syncthreads();
  }

  float bv[4];
#pragma unroll
  for (int n = 0; n < 4; ++n) bv[n] = bias[n0 + wc * 64 + n * 16 + lr];

#pragma unroll
  for (int m = 0; m < 4; ++m)
#pragma unroll
    for (int n = 0; n < 4; ++n) {
      const int col = n0 + wc * 64 + n * 16 + lr;
#pragma unroll
      for (int j = 0; j < 4; ++j) {
        const int row = m0 + wr * 64 + m * 16 + lg * 4 + j;
        const float v = acc[m][n][j] + bv[n];
        if (out_bf16)
          ((__hip_bfloat16*)Cp)[(size_t)row * N + col] = __float2bfloat16(v);
        else
          ((float*)Cp)[(size_t)row * N + col] = v;
      }
    }
}

// ------------------------------------------------------------- flash attention
// QBLK=128 (4 waves x 32 rows), staged KV tile = 128 (two 64-halves),
// K LDS-staged (dbuf, counted vmcnt), V direct-from-global (L2-resident),
// static-max softmax (f32 range covers it), row-sum via ones-MFMA.
#define ATT_SL2E 0.12751740f  // (1/sqrt(128)) * log2(e)

__global__ __launch_bounds__(256, 2) void k_attn(
    const __hip_bfloat16* __restrict__ qkv, const __hip_bfloat16* __restrict__ vT,
    __hip_bfloat16* __restrict__ ctx) {
  __shared__ __align__(16) __hip_bfloat16 Ks[2][128 * 128];
  __shared__ __align__(16) __hip_bfloat16 Ps[4][32 * 64];
  const int tid = threadIdx.x;
  const int lane = tid & 63, w = tid >> 6;
  const int lr = lane & 15, lg = lane >> 4;
  const int bid = blockIdx.x;
  const int lo = bid & 255, hi = bid >> 8;
  const int bh = lo & 31, qsel = lo >> 5;  // qsel in 0..7
  const int b = bh >> 4, h = bh & 15;
  const int qt = hi ? qsel : 15 - qsel;  // CU pairing: constant total work

  const __hip_bfloat16* kbase = qkv + (size_t)b * 2048 * 6144 + 2048 + h * 128;
  const __hip_bfloat16* vbase = vT + (size_t)(b * 16 + h) * 128 * 2048;

  auto STAGE = [&](int bufi, int kt) {
    const int kv0 = kt * 128;
#pragma unroll
    for (int q = 0; q < 8; ++q) {
      const int slot = q * 256 + tid;
      const int row = slot >> 4, u = slot & 15;
      GLD16(&Ks[bufi][slot * 8],
            kbase + (size_t)(kv0 + row) * 6144 + ((u ^ (row & 15)) * 8));
    }
  };

  // Q fragments: 32 rows/wave
  const __hip_bfloat16* qbase =
      qkv + (size_t)(b * 2048 + qt * 128 + w * 32) * 6144 + h * 128;
  bx8 qf[2][4];
#pragma unroll
  for (int m = 0; m < 2; ++m)
#pragma unroll
    for (int ks = 0; ks < 4; ++ks)
      qf[m][ks] = *(const bx8*)(qbase + (size_t)(m * 16 + lr) * 6144 + ks * 32 + lg * 8);

  bx8 vones;
#pragma unroll
  for (int e = 0; e < 8; ++e) vones[e] = (short)0x3F80;  // bf16 1.0

  fx4 oacc[2][8], lacc[2];
#pragma unroll
  for (int m = 0; m < 2; ++m) {
    lacc[m] = (fx4)(0.0f);
#pragma unroll
    for (int d = 0; d < 8; ++d) oacc[m][d] = (fx4)(0.0f);
  }

  const int ntile = qt + 1;
  const int qrow0 = qt * 128 + w * 32;

  STAGE(0, 0);
  for (int kt = 0; kt < ntile; ++kt) {
    const int cur = kt & 1;
    if (kt + 1 < ntile) {
      STAGE(cur ^ 1, kt + 1);
      asm volatile("s_waitcnt vmcnt(8)" ::: "memory");
    } else {
      asm volatile("s_waitcnt vmcnt(0)" ::: "memory");
    }
    __builtin_amdgcn_s_barrier();
    asm volatile("" ::: "memory");

#pragma unroll
    for (int h2 = 0; h2 < 2; ++h2) {
      const int kv0 = kt * 128 + h2 * 64;
      if (kv0 > qrow0 + 31) continue;  // wave fully masked (wave-uniform)

      // ---- QK^T over this 64-kv half
      fx4 sacc[2][4];
#pragma unroll
      for (int n = 0; n < 4; ++n) {
        sacc[0][n] = (fx4)(0.0f);
        sacc[1][n] = (fx4)(0.0f);
      }
      __builtin_amdgcn_s_setprio(1);
#pragma unroll
      for (int n = 0; n < 4; ++n) {
        const int r = h2 * 64 + n * 16 + lr;
#pragma unroll
        for (int ks = 0; ks < 4; ++ks) {
          const bx8 kf = *(const bx8*)&Ks[cur][r * 128 + (((ks * 4 + lg) ^ lr) * 8)];
          sacc[0][n] =
              __builtin_amdgcn_mfma_f32_16x16x32_bf16(qf[0][ks], kf, sacc[0][n], 0, 0, 0);
          sacc[1][n] =
              __builtin_amdgcn_mfma_f32_16x16x32_bf16(qf[1][ks], kf, sacc[1][n], 0, 0, 0);
        }
      }
      __builtin_amdgcn_s_setprio(0);

      // ---- static-max softmax: p = exp2(min(s*scale*log2e, 60)); masked -> 0
      const bool needmask = (kv0 + 63) > qrow0;  // wave-uniform
#pragma unroll
      for (int n = 0; n < 4; ++n) {
        const int kvi = kv0 + n * 16 + lr;
#pragma unroll
        for (int m = 0; m < 2; ++m)
#pragma unroll
          for (int j = 0; j < 4; ++j) {
            float v = sacc[m][n][j] * ATT_SL2E;
            if (needmask) {
              const int qi = qrow0 + m * 16 + lg * 4 + j;
              if (kvi > qi) v = -200.0f;
            }
            const float p = exp2f(fminf(v, 60.0f));
            const int r = m * 16 + lg * 4 + j, c = n * 16 + lr;
            const int c2 = (c & 7) | (((c >> 3) ^ (r & 7)) << 3);
            Ps[w][r * 64 + c2] = __float2bfloat16(p);
          }
      }

      // ---- PV (V direct from global) + row-sum via ones-MFMA
      __builtin_amdgcn_s_setprio(1);
#pragma unroll
      for (int ks2 = 0; ks2 < 2; ++ks2) {
        const int u = ((ks2 * 4 + lg) ^ (lr & 7)) * 8;
        const bx8 pf0 = *(const bx8*)&Ps[w][(0 * 16 + lr) * 64 + u];
        const bx8 pf1 = *(const bx8*)&Ps[w][(1 * 16 + lr) * 64 + u];
        lacc[0] = __builtin_amdgcn_mfma_f32_16x16x32_bf16(pf0, vones, lacc[0], 0, 0, 0);
        lacc[1] = __builtin_amdgcn_mfma_f32_16x16x32_bf16(pf1, vones, lacc[1], 0, 0, 0);
#pragma unroll
        for (int dn = 0; dn < 8; ++dn) {
          const bx8 vf = *(const bx8*)(vbase + (size_t)(dn * 16 + lr) * 2048 + kv0 +
                                       ks2 * 32 + lg * 8);
          oacc[0][dn] =
              __builtin_amdgcn_mfma_f32_16x16x32_bf16(pf0, vf, oacc[0][dn], 0, 0, 0);
          oacc[1][dn] =
              __builtin_amdgcn_mfma_f32_16x16x32_bf16(pf1, vf, oacc[1][dn], 0, 0, 0);
        }
      }
      __builtin_amdgcn_s_setprio(0);
    }
    __builtin_amdgcn_s_barrier();  // all waves done reading Ks[cur]
    asm volatile("" ::: "memory");
  }

  // ---- output
  float rl[2][4];
#pragma unroll
  for (int m = 0; m < 2; ++m)
#pragma unroll
    for (int j = 0; j < 4; ++j) rl[m][j] = 1.0f / lacc[m][j];
#pragma unroll
  for (int m = 0; m < 2; ++m)
#pragma unroll
    for (int dn = 0; dn < 8; ++dn)
#pragma unroll
      for (int j = 0; j < 4; ++j) {
        const int row = qt * 128 + w * 32 + m * 16 + lg * 4 + j;
        ctx[(size_t)(b * 2048 + row) * 2048 + h * 128 + dn * 16 + lr] =
            __float2bfloat16(oacc[m][dn][j] * rl[m][j]);
      }
}

// ------------------------------------------------------------------- launcher
extern "C" void kernel_launch(void* const* d_in, const int* in_sizes, int n_in,
                              void* d_out, int out_size, void* d_ws, size_t ws_size,
                              hipStream_t stream) {
  const float* x = (const float*)d_in[0];
  const float* Wqkv = (const float*)d_in[1];
  const float* bqkv = (const float*)d_in[2];
  const float* Wout = (const float*)d_in[3];
  const float* bout = (const float*)d_in[4];
  float* out = (float*)d_out;

  char* ws = (char*)d_ws;
  __hip_bfloat16* xb    = (__hip_bfloat16*)(ws + 0);          // 16 MiB
  __hip_bfloat16* wqkvT = (__hip_bfloat16*)(ws + 16777216);   // 24 MiB
  __hip_bfloat16* woutT = (__hip_bfloat16*)(ws + 41943040);   // 8 MiB
  __hip_bfloat16* qkvb  = (__hip_bfloat16*)(ws + 50331648);   // 48 MiB
  __hip_bfloat16* vTb   = (__hip_bfloat16*)(ws + 100663296);  // 16 MiB
  __hip_bfloat16* ctxb  = (__hip_bfloat16*)(ws + 117440512);  // 16 MiB
  float* cosT = (float*)(ws + 134217728);                     // 512 KiB
  float* sinT = (float*)(ws + 134742016);                     // 512 KiB

  k_cast<<<8192, 256, 0, stream>>>(x, xb, 2097152);
  k_tcast<<<dim3(192, 64), dim3(32, 8), 0, stream>>>(Wqkv, wqkvT, 2048, 6144);
  k_tcast<<<dim3(64, 64), dim3(32, 8), 0, stream>>>(Wout, woutT, 2048, 2048);
  k_ropetab<<<512, 256, 0, stream>>>(cosT, sinT);
  k_gemm_bt<<<dim3(48, 32), 256, 0, stream>>>(xb, wqkvT, bqkv, qkvb, 4096, 6144,
                                              2048, 1);
  k_rope<<<4096, 256, 0, stream>>>(qkvb, cosT, sinT);
  k_vtrans<<<dim3(64, 4, 32), dim3(32, 8), 0, stream>>>(qkvb, vTb);
  k_attn<<<512, 256, 0, stream>>>(qkvb, vTb, ctxb);
  k_gemm_bt<<<dim3(16, 32), 256, 0, stream>>>(ctxb, woutT, bout, out, 4096, 2048,
                                              2048, 0);
}